// Round 5
// baseline (277.473 us; speedup 1.0000x reference)
//
#include <hip/hip_runtime.h>
#include <math.h>

#define N 4096
#define F 256
#define NT 32            // N / BM
#define BM 128
#define BK 32
#define NTRI 528         // NT*(NT+1)/2 upper-tri tiles per batch
#define NWG  1056        // 2 * NTRI, == 8 * 132 (XCD-bijective)

typedef short short8 __attribute__((ext_vector_type(8)));
typedef float f32x4  __attribute__((ext_vector_type(4)));

typedef const __attribute__((address_space(1))) unsigned int guint_t;
typedef __attribute__((address_space(3))) unsigned int luint_t;

__device__ __forceinline__ void gload_lds16(const void* g, void* l) {
    // async global->LDS, 16B per lane; LDS dest = wave-uniform base + lane*16
    __builtin_amdgcn_global_load_lds((guint_t*)g, (luint_t*)l, 16, 0, 0);
}

__device__ __forceinline__ unsigned short f2bf(float x) {
    unsigned u = __float_as_uint(x);
    unsigned r = (u + 0x7fff + ((u >> 16) & 1)) >> 16;   // RNE
    return (unsigned short)r;
}
__device__ __forceinline__ float bf2f(unsigned short x) {
    return __uint_as_float(((unsigned)x) << 16);
}

// ------- prep: Y=X*W; split y = hi + lo (bf16 pair); sq = ||Y_i||^2 --------
__global__ __launch_bounds__(256)
void prep_kernel(const float* __restrict__ X1, const float* __restrict__ X2,
                 const float* __restrict__ W,
                 unsigned short* __restrict__ Yhi, unsigned short* __restrict__ Ylo,
                 float* __restrict__ sqg)
{
    const int t = threadIdx.x;            // 256 == F
    const int rid0 = blockIdx.x * 8;      // 8 rows per block
    const float w = W[t];
    __shared__ float red[8][4];
    const int lane = t & 63, wv = t >> 6;
    #pragma unroll
    for (int r = 0; r < 8; ++r) {
        int rid = rid0 + r;
        int b = rid >> 12, row = rid & (N - 1);
        const float* X = b ? X2 : X1;
        float y = X[(size_t)row * F + t] * w;
        unsigned short h = f2bf(y);
        float lf = y - bf2f(h);
        size_t off = (size_t)rid * F + t;
        Yhi[off] = h;
        Ylo[off] = f2bf(lf);
        float s = y * y;
        #pragma unroll
        for (int o = 32; o > 0; o >>= 1) s += __shfl_down(s, o);
        if (lane == 0) red[r][wv] = s;
    }
    __syncthreads();
    if (t < 8) {
        sqg[rid0 + t] = red[t][0] + red[t][1] + red[t][2] + red[t][3];
    }
}

// ---- fused tile kernel: split-bf16 MFMA Gram tile -> KL partials ----------
// Compact triangular grid; single 32KB LDS buffer -> 5 blocks/CU (TLP-first).
__global__ __launch_bounds__(256, 5)
void tsne_tile_kernel(const unsigned short* __restrict__ Yhi,
                      const unsigned short* __restrict__ Ylo,
                      const float* __restrict__ sqg,
                      const float* __restrict__ P1, const float* __restrict__ P2,
                      double* __restrict__ pS, double* __restrict__ pA,
                      double* __restrict__ pB)
{
    // XCD-bijective swizzle: 1056 = 8 * 132; each XCD gets a contiguous run
    const int wg  = (blockIdx.x & 7) * 132 + (blockIdx.x >> 3);
    const int bz  = wg >= NTRI;
    int r = wg - bz * NTRI;
    int by = 0;
    while (r >= NT - by) { r -= NT - by; ++by; }   // triangular decode
    const int bx = by + r;

    const float* P  = bz ? P2 : P1;
    const unsigned short* Ah = Yhi + (size_t)bz * N * F;
    const unsigned short* Al = Ylo + (size_t)bz * N * F;
    const float* sq = sqg + bz * N;
    const float wgt = (bx == by) ? 1.0f : 2.0f;

    __shared__ unsigned short sbuf[4][BM * BK];    // Ah,Al,Bh,Bl : 32 KB

    const int t = threadIdx.x;
    const int lane = t & 63, w = t >> 6;
    const int wx = w & 1, wy = w >> 1;             // 2x2 waves, 64x64 each

    f32x4 acc[4][4];
    #pragma unroll
    for (int fm = 0; fm < 4; ++fm)
        #pragma unroll
        for (int fn = 0; fn < 4; ++fn) acc[fm][fn] = (f32x4){0.f, 0.f, 0.f, 0.f};

    const int arow = by * BM, brow = bx * BM;
    const int c = lane >> 4, mr = lane & 15;

    for (int ks = 0; ks < F / BK; ++ks) {
        const int k0 = ks * BK;
        // stage 128x32 hi/lo A+B (chunk swizzle: slot kl holds k-chunk
        // kl ^ ((row>>1)&3) -> conflict-free b128 reads, counter-verified)
        #pragma unroll
        for (int it = 0; it < 2; ++it) {
            int cid = it * 256 + w * 64 + lane;
            int row = cid >> 2;
            int kl  = cid & 3;
            int kg  = kl ^ ((row >> 1) & 3);
            int ldsoff = (it * 256 + w * 64) * 8;
            size_t ga = (size_t)(arow + row) * F + k0 + kg * 8;
            size_t gb = (size_t)(brow + row) * F + k0 + kg * 8;
            gload_lds16(Ah + ga, &sbuf[0][ldsoff]);
            gload_lds16(Al + ga, &sbuf[1][ldsoff]);
            gload_lds16(Ah + gb, &sbuf[2][ldsoff]);
            gload_lds16(Al + gb, &sbuf[3][ldsoff]);
        }
        __syncthreads();   // stage complete (vmcnt drain; TLP covers it)

        short8 ah[4], al[4], bh[4], bl[4];
        #pragma unroll
        for (int fm = 0; fm < 4; ++fm) {
            int row = wy * 64 + fm * 16 + mr;
            int ad = row * BK + ((c ^ ((row >> 1) & 3)) * 8);
            ah[fm] = *(const short8*)&sbuf[0][ad];
            al[fm] = *(const short8*)&sbuf[1][ad];
        }
        #pragma unroll
        for (int fn = 0; fn < 4; ++fn) {
            int row = wx * 64 + fn * 16 + mr;
            int ad = row * BK + ((c ^ ((row >> 1) & 3)) * 8);
            bh[fn] = *(const short8*)&sbuf[2][ad];
            bl[fn] = *(const short8*)&sbuf[3][ad];
        }
        #pragma unroll
        for (int fm = 0; fm < 4; ++fm)
            #pragma unroll
            for (int fn = 0; fn < 4; ++fn) {
                acc[fm][fn] = __builtin_amdgcn_mfma_f32_16x16x32_bf16(ah[fm], bh[fn], acc[fm][fn], 0, 0, 0);
                acc[fm][fn] = __builtin_amdgcn_mfma_f32_16x16x32_bf16(ah[fm], bl[fn], acc[fm][fn], 0, 0, 0);
                acc[fm][fn] = __builtin_amdgcn_mfma_f32_16x16x32_bf16(al[fm], bh[fn], acc[fm][fn], 0, 0, 0);
            }
        __syncthreads();   // all reads done before next stage overwrites
    }

    // ---------------- epilogue ----------------
    const int q = lane >> 4, nn = lane & 15;
    const int gi0 = arow + wy * 64, gj0 = brow + wx * 64;
    float sp = 0.f, ap = 0.f, bp = 0.f;
    #pragma unroll
    for (int fm = 0; fm < 4; ++fm) {
        float sqi[4];
        #pragma unroll
        for (int rr = 0; rr < 4; ++rr) sqi[rr] = sq[gi0 + fm * 16 + q * 4 + rr];
        #pragma unroll
        for (int fn = 0; fn < 4; ++fn) {
            int j = gj0 + fn * 16 + nn;
            float sqj = sq[j];
            #pragma unroll
            for (int rr = 0; rr < 4; ++rr) {
                int i = gi0 + fm * 16 + q * 4 + rr;
                float one_d2 = 1.0f + fmaxf(sqi[rr] + sqj - 2.0f * acc[fm][fn][rr], 0.0f);
                if (i != j) {
                    float p = P[(size_t)i * N + j];
                    sp += __builtin_amdgcn_rcpf(one_d2);   // temp (feeds log S only)
                    ap += p * __logf(p * one_d2);          // P*log(P*(1+d2))
                    bp += p;
                }
            }
        }
    }
    sp *= wgt; ap *= wgt; bp *= wgt;

    #pragma unroll
    for (int o = 32; o > 0; o >>= 1) {
        sp += __shfl_down(sp, o);
        ap += __shfl_down(ap, o);
        bp += __shfl_down(bp, o);
    }
    float* red = (float*)&sbuf[0][0];    // reuse LDS (k-loop fully done)
    if (lane == 0) { red[w] = sp; red[4 + w] = ap; red[8 + w] = bp; }
    __syncthreads();
    if (t == 0) {
        pS[wg] = (double)(red[0] + red[1] + red[2] + red[3]);
        pA[wg] = (double)(red[4] + red[5] + red[6] + red[7]);
        pB[wg] = (double)(red[8] + red[9] + red[10] + red[11]);
    }
}

// ---------------- finish: kl_b = A_b + B_b * log(S_b); out = mean -----------
__global__ __launch_bounds__(256)
void finish_kernel(const double* __restrict__ pS, const double* __restrict__ pA,
                   const double* __restrict__ pB, float* __restrict__ out)
{
    int t = threadIdx.x;
    double s0 = 0, a0 = 0, b0 = 0, s1 = 0, a1 = 0, b1 = 0;
    for (int i = t; i < NTRI; i += 256) {
        s0 += pS[i];        a0 += pA[i];        b0 += pB[i];
        s1 += pS[i + NTRI]; a1 += pA[i + NTRI]; b1 += pB[i + NTRI];
    }
    __shared__ double red[6][256];
    red[0][t] = s0; red[1][t] = a0; red[2][t] = b0;
    red[3][t] = s1; red[4][t] = a1; red[5][t] = b1;
    __syncthreads();
    for (int o = 128; o > 0; o >>= 1) {
        if (t < o) {
            #pragma unroll
            for (int qd = 0; qd < 6; ++qd) red[qd][t] += red[qd][t + o];
        }
        __syncthreads();
    }
    if (t == 0) {
        double kl1 = red[1][0] + red[2][0] * log(red[0][0]);
        double kl2 = red[4][0] + red[5][0] * log(red[3][0]);
        out[0] = (float)((kl1 + kl2) * 0.5);
    }
}

extern "C" void kernel_launch(void* const* d_in, const int* in_sizes, int n_in,
                              void* d_out, int out_size, void* d_ws, size_t ws_size,
                              hipStream_t stream)
{
    const float* P1 = (const float*)d_in[0];
    const float* P2 = (const float*)d_in[1];
    const float* X1 = (const float*)d_in[2];
    const float* X2 = (const float*)d_in[3];
    const float* W  = (const float*)d_in[4];
    float* out = (float*)d_out;

    unsigned short* Yhi = (unsigned short*)d_ws;            // 2*N*F ushort
    unsigned short* Ylo = Yhi + (size_t)2 * N * F;          // 2*N*F ushort
    float* sq = (float*)(Ylo + (size_t)2 * N * F);          // 2*N floats
    double* pS = (double*)(sq + 2 * N);                     // 8-aligned
    double* pA = pS + NWG;
    double* pB = pA + NWG;

    prep_kernel<<<(2 * N) / 8, 256, 0, stream>>>(X1, X2, W, Yhi, Ylo, sq);
    tsne_tile_kernel<<<NWG, 256, 0, stream>>>(Yhi, Ylo, sq, P1, P2, pS, pA, pB);
    finish_kernel<<<1, 256, 0, stream>>>(pS, pA, pB, out);
}

// Round 6
// 190.607 us; speedup vs baseline: 1.4557x; 1.4557x over previous
//
#include <hip/hip_runtime.h>
#include <math.h>

#define N 4096
#define F 256
#define NT 32            // N / BM
#define BM 128
#define BK 32
#define NTRI 528         // NT*(NT+1)/2 upper-tri tiles per batch
#define NWG  1056        // 2 * NTRI, == 8 * 132 (XCD-bijective)

typedef short short8 __attribute__((ext_vector_type(8)));
typedef float f32x4  __attribute__((ext_vector_type(4)));

typedef const __attribute__((address_space(1))) unsigned int guint_t;
typedef __attribute__((address_space(3))) unsigned int luint_t;

__device__ __forceinline__ void gload_lds16(const void* g, void* l) {
    // async global->LDS, 16B per lane; LDS dest = wave-uniform base + lane*16
    __builtin_amdgcn_global_load_lds((guint_t*)g, (luint_t*)l, 16, 0, 0);
}

__device__ __forceinline__ unsigned short f2bf(float x) {
    unsigned u = __float_as_uint(x);
    unsigned r = (u + 0x7fff + ((u >> 16) & 1)) >> 16;   // RNE
    return (unsigned short)r;
}
__device__ __forceinline__ float bf2f(unsigned short x) {
    return __uint_as_float(((unsigned)x) << 16);
}

// ------- prep: Y=X*W; split y = hi + lo (bf16 pair); sq = ||Y_i||^2 --------
__global__ __launch_bounds__(256)
void prep_kernel(const float* __restrict__ X1, const float* __restrict__ X2,
                 const float* __restrict__ W,
                 unsigned short* __restrict__ Yhi, unsigned short* __restrict__ Ylo,
                 float* __restrict__ sqg)
{
    const int t = threadIdx.x;            // 256 == F
    const int rid0 = blockIdx.x * 8;      // 8 rows per block
    const float w = W[t];
    __shared__ float red[8][4];
    const int lane = t & 63, wv = t >> 6;
    #pragma unroll
    for (int r = 0; r < 8; ++r) {
        int rid = rid0 + r;
        int b = rid >> 12, row = rid & (N - 1);
        const float* X = b ? X2 : X1;
        float y = X[(size_t)row * F + t] * w;
        unsigned short h = f2bf(y);
        float lf = y - bf2f(h);
        size_t off = (size_t)rid * F + t;
        Yhi[off] = h;
        Ylo[off] = f2bf(lf);
        float s = y * y;
        #pragma unroll
        for (int o = 32; o > 0; o >>= 1) s += __shfl_down(s, o);
        if (lane == 0) red[r][wv] = s;
    }
    __syncthreads();
    if (t < 8) {
        sqg[rid0 + t] = red[t][0] + red[t][1] + red[t][2] + red[t][3];
    }
}

// ---- fused tile kernel: split-bf16 MFMA Gram tile -> KL partials ----------
// Compact triangular grid; single 32KB LDS buffer.
// __launch_bounds__(256,4): 4 waves/SIMD -> VGPR cap 128 (acc stays in regs;
// (256,5) clamped VGPR to 48 and spilled the accumulator -> 208MB scratch).
__global__ __launch_bounds__(256, 4)
void tsne_tile_kernel(const unsigned short* __restrict__ Yhi,
                      const unsigned short* __restrict__ Ylo,
                      const float* __restrict__ sqg,
                      const float* __restrict__ P1, const float* __restrict__ P2,
                      double* __restrict__ pS, double* __restrict__ pA,
                      double* __restrict__ pB)
{
    // XCD-bijective swizzle: 1056 = 8 * 132; each XCD gets a contiguous run
    const int wg  = (blockIdx.x & 7) * 132 + (blockIdx.x >> 3);
    const int bz  = wg >= NTRI;
    int r = wg - bz * NTRI;
    int by = 0;
    while (r >= NT - by) { r -= NT - by; ++by; }   // triangular decode
    const int bx = by + r;

    const float* P  = bz ? P2 : P1;
    const unsigned short* Ah = Yhi + (size_t)bz * N * F;
    const unsigned short* Al = Ylo + (size_t)bz * N * F;
    const float* sq = sqg + bz * N;
    const float wgt = (bx == by) ? 1.0f : 2.0f;

    __shared__ unsigned short sbuf[4][BM * BK];    // Ah,Al,Bh,Bl : 32 KB

    const int t = threadIdx.x;
    const int lane = t & 63, w = t >> 6;
    const int wx = w & 1, wy = w >> 1;             // 2x2 waves, 64x64 each

    f32x4 acc[4][4];
    #pragma unroll
    for (int fm = 0; fm < 4; ++fm)
        #pragma unroll
        for (int fn = 0; fn < 4; ++fn) acc[fm][fn] = (f32x4){0.f, 0.f, 0.f, 0.f};

    const int arow = by * BM, brow = bx * BM;
    const int c = lane >> 4, mr = lane & 15;

    for (int ks = 0; ks < F / BK; ++ks) {
        const int k0 = ks * BK;
        // stage 128x32 hi/lo A+B (chunk swizzle: slot kl holds k-chunk
        // kl ^ ((row>>1)&3) -> conflict-free b128 reads, counter-verified)
        #pragma unroll
        for (int it = 0; it < 2; ++it) {
            int cid = it * 256 + w * 64 + lane;
            int row = cid >> 2;
            int kl  = cid & 3;
            int kg  = kl ^ ((row >> 1) & 3);
            int ldsoff = (it * 256 + w * 64) * 8;
            size_t ga = (size_t)(arow + row) * F + k0 + kg * 8;
            size_t gb = (size_t)(brow + row) * F + k0 + kg * 8;
            gload_lds16(Ah + ga, &sbuf[0][ldsoff]);
            gload_lds16(Al + ga, &sbuf[1][ldsoff]);
            gload_lds16(Ah + gb, &sbuf[2][ldsoff]);
            gload_lds16(Al + gb, &sbuf[3][ldsoff]);
        }
        __syncthreads();   // stage complete (vmcnt drain; TLP covers it)

        short8 ah[4], al[4], bh[4], bl[4];
        #pragma unroll
        for (int fm = 0; fm < 4; ++fm) {
            int row = wy * 64 + fm * 16 + mr;
            int ad = row * BK + ((c ^ ((row >> 1) & 3)) * 8);
            ah[fm] = *(const short8*)&sbuf[0][ad];
            al[fm] = *(const short8*)&sbuf[1][ad];
        }
        #pragma unroll
        for (int fn = 0; fn < 4; ++fn) {
            int row = wx * 64 + fn * 16 + mr;
            int ad = row * BK + ((c ^ ((row >> 1) & 3)) * 8);
            bh[fn] = *(const short8*)&sbuf[2][ad];
            bl[fn] = *(const short8*)&sbuf[3][ad];
        }
        #pragma unroll
        for (int fm = 0; fm < 4; ++fm)
            #pragma unroll
            for (int fn = 0; fn < 4; ++fn) {
                acc[fm][fn] = __builtin_amdgcn_mfma_f32_16x16x32_bf16(ah[fm], bh[fn], acc[fm][fn], 0, 0, 0);
                acc[fm][fn] = __builtin_amdgcn_mfma_f32_16x16x32_bf16(ah[fm], bl[fn], acc[fm][fn], 0, 0, 0);
                acc[fm][fn] = __builtin_amdgcn_mfma_f32_16x16x32_bf16(al[fm], bh[fn], acc[fm][fn], 0, 0, 0);
            }
        __syncthreads();   // all reads done before next stage overwrites
    }

    // ---------------- epilogue ----------------
    const int q = lane >> 4, nn = lane & 15;
    const int gi0 = arow + wy * 64, gj0 = brow + wx * 64;
    float sp = 0.f, ap = 0.f, bp = 0.f;
    #pragma unroll
    for (int fm = 0; fm < 4; ++fm) {
        float sqi[4];
        #pragma unroll
        for (int rr = 0; rr < 4; ++rr) sqi[rr] = sq[gi0 + fm * 16 + q * 4 + rr];
        #pragma unroll
        for (int fn = 0; fn < 4; ++fn) {
            int j = gj0 + fn * 16 + nn;
            float sqj = sq[j];
            #pragma unroll
            for (int rr = 0; rr < 4; ++rr) {
                int i = gi0 + fm * 16 + q * 4 + rr;
                float one_d2 = 1.0f + fmaxf(sqi[rr] + sqj - 2.0f * acc[fm][fn][rr], 0.0f);
                if (i != j) {
                    float p = P[(size_t)i * N + j];
                    sp += __builtin_amdgcn_rcpf(one_d2);   // temp (feeds log S only)
                    ap += p * __logf(p * one_d2);          // P*log(P*(1+d2))
                    bp += p;
                }
            }
        }
    }
    sp *= wgt; ap *= wgt; bp *= wgt;

    #pragma unroll
    for (int o = 32; o > 0; o >>= 1) {
        sp += __shfl_down(sp, o);
        ap += __shfl_down(ap, o);
        bp += __shfl_down(bp, o);
    }
    float* red = (float*)&sbuf[0][0];    // reuse LDS (k-loop fully done)
    if (lane == 0) { red[w] = sp; red[4 + w] = ap; red[8 + w] = bp; }
    __syncthreads();
    if (t == 0) {
        pS[wg] = (double)(red[0] + red[1] + red[2] + red[3]);
        pA[wg] = (double)(red[4] + red[5] + red[6] + red[7]);
        pB[wg] = (double)(red[8] + red[9] + red[10] + red[11]);
    }
}

// ---------------- finish: kl_b = A_b + B_b * log(S_b); out = mean -----------
__global__ __launch_bounds__(256)
void finish_kernel(const double* __restrict__ pS, const double* __restrict__ pA,
                   const double* __restrict__ pB, float* __restrict__ out)
{
    int t = threadIdx.x;
    double s0 = 0, a0 = 0, b0 = 0, s1 = 0, a1 = 0, b1 = 0;
    for (int i = t; i < NTRI; i += 256) {
        s0 += pS[i];        a0 += pA[i];        b0 += pB[i];
        s1 += pS[i + NTRI]; a1 += pA[i + NTRI]; b1 += pB[i + NTRI];
    }
    __shared__ double red[6][256];
    red[0][t] = s0; red[1][t] = a0; red[2][t] = b0;
    red[3][t] = s1; red[4][t] = a1; red[5][t] = b1;
    __syncthreads();
    for (int o = 128; o > 0; o >>= 1) {
        if (t < o) {
            #pragma unroll
            for (int qd = 0; qd < 6; ++qd) red[qd][t] += red[qd][t + o];
        }
        __syncthreads();
    }
    if (t == 0) {
        double kl1 = red[1][0] + red[2][0] * log(red[0][0]);
        double kl2 = red[4][0] + red[5][0] * log(red[3][0]);
        out[0] = (float)((kl1 + kl2) * 0.5);
    }
}

extern "C" void kernel_launch(void* const* d_in, const int* in_sizes, int n_in,
                              void* d_out, int out_size, void* d_ws, size_t ws_size,
                              hipStream_t stream)
{
    const float* P1 = (const float*)d_in[0];
    const float* P2 = (const float*)d_in[1];
    const float* X1 = (const float*)d_in[2];
    const float* X2 = (const float*)d_in[3];
    const float* W  = (const float*)d_in[4];
    float* out = (float*)d_out;

    unsigned short* Yhi = (unsigned short*)d_ws;            // 2*N*F ushort
    unsigned short* Ylo = Yhi + (size_t)2 * N * F;          // 2*N*F ushort
    float* sq = (float*)(Ylo + (size_t)2 * N * F);          // 2*N floats
    double* pS = (double*)(sq + 2 * N);                     // 8-aligned
    double* pA = pS + NWG;
    double* pB = pA + NWG;

    prep_kernel<<<(2 * N) / 8, 256, 0, stream>>>(X1, X2, W, Yhi, Ylo, sq);
    tsne_tile_kernel<<<NWG, 256, 0, stream>>>(Yhi, Ylo, sq, P1, P2, pS, pA, pB);
    finish_kernel<<<1, 256, 0, stream>>>(pS, pA, pB, out);
}